// Round 7
// baseline (122.295 us; speedup 1.0000x reference)
//
#include <hip/hip_runtime.h>

#define NB 4
#define SS 2048
#define DMODEL 1024
#define DHEAD 64
// SCALE = sqrt(1024) = 32 exactly; folded into Wt for mode 0 (bias scaled in k1b).
// Softmax WITHOUT max subtraction: s ~ N(0,0.25), exp safe in f32.
// Softmax over the QUERY axis (reference quirk): r[k] = 1/sum_q exp(s[q,k]).
// out = (exp(S).*r) @ V  +  mask @ V   (two GEMMs; no P materialization)
// R7 theme: every kernel gets (a) coalesced HBM access (LDS-staged where needed)
// and (b) >=4 blocks/CU via k-splits, fixing the 16-row-scatter + low-occupancy
// latency disease diagnosed in R6.

typedef __bf16 bf16x8 __attribute__((ext_vector_type(8)));
typedef __bf16 bf16x4 __attribute__((ext_vector_type(4)));
typedef float f32x4 __attribute__((ext_vector_type(4)));

#define MFMA16(a, b, c) __builtin_amdgcn_mfma_f32_16x16x32_bf16((a), (b), (c), 0, 0, 0)

// ---------------- Kernel 0: transpose W -> Wt[mode][n][k] bf16 ----------------
__global__ __launch_bounds__(256) void k0_wt(
    const float* __restrict__ Wq, const float* __restrict__ Wk,
    const float* __restrict__ Wv, __bf16* __restrict__ Wt)
{
    int t = blockIdx.x * 256 + threadIdx.x;
    int m = t >> 13;
    int rem = t & 8191;
    int n  = rem >> 7;
    int k0 = (rem & 127) << 3;
    const float* W = (m == 0) ? Wq : (m == 1 ? Wk : Wv);
    const float s = (m == 0) ? 0.03125f : 1.0f;
    __bf16* o = Wt + ((size_t)m * 64 + n) * DMODEL + k0;
    #pragma unroll
    for (int i = 0; i < 8; ++i)
        o[i] = (__bf16)(W[(size_t)(k0 + i) * DHEAD + n] * s);
}

// ---------------- Kernel 1: fused Q/K/V projection (K-split 2) --------------
// grid (512,2): 512 row-tiles x khalf. Block 256 (4 waves, each 128-k).
// x tile [16][512] staged f32->bf16 via coalesced loads into LDS; A-frags via
// ds_read_b128; Wt B-frags from L2. f32 partials written per khalf; k1b
// combines. LDS 36.9KB -> 4 blocks/CU = 16 waves/CU (vs 2 blocks before).
__global__ __launch_bounds__(256, 4) void k1_fused(
    const float* __restrict__ x, const __bf16* __restrict__ Wt,
    float* __restrict__ partQK, float* __restrict__ partV)
{
    __shared__ char smem[36864];              // stage 16x520 bf16 (16.6KB) | red alias (36.9KB)
    __bf16* stage = (__bf16*)smem;
    const int tid = threadIdx.x;
    const int wid = tid >> 6;
    const int lane = tid & 63;
    const int l15 = lane & 15;
    const int g = lane >> 4;
    const int row0 = blockIdx.x * 16;
    const int khalf = blockIdx.y;

    // stage x[row0..+16][khalf*512..+512] f32 -> bf16, fully coalesced
    {
        const float* xsrc = x + (size_t)row0 * DMODEL + khalf * 512;
        #pragma unroll
        for (int it = 0; it < 8; ++it) {
            int idx = it * 256 + tid;         // 0..2047
            int row = idx >> 7;               // 128 thr/row
            int col = (idx & 127) * 4;
            f32x4 v = *(const f32x4*)(xsrc + (size_t)row * DMODEL + col);
            bf16x4 b4;
            #pragma unroll
            for (int i = 0; i < 4; ++i) b4[i] = (__bf16)v[i];
            *(bf16x4*)(stage + row * 520 + col) = b4;
        }
    }
    __syncthreads();

    f32x4 acc[12];
    #pragma unroll
    for (int f = 0; f < 12; ++f) acc[f] = (f32x4){0.f, 0.f, 0.f, 0.f};

    const __bf16* wbase = Wt + (size_t)l15 * DMODEL + khalf * 512 + wid * 128 + g * 8;
    #pragma unroll
    for (int c = 0; c < 4; ++c) {
        bf16x8 af = *(const bf16x8*)(stage + l15 * 520 + wid * 128 + c * 32 + g * 8);
        #pragma unroll
        for (int f = 0; f < 12; ++f) {
            const int md = f >> 2, nt = f & 3;
            bf16x8 bfr = *(const bf16x8*)(wbase + (size_t)(md * 64 + nt * 16) * DMODEL + c * 32);
            acc[f] = MFMA16(af, bfr, acc[f]);
        }
    }
    __syncthreads();                          // ds_reads done; alias red over stage
    f32x4* red = (f32x4*)smem;                // [3][12][64]
    if (wid != 0) {
        #pragma unroll
        for (int f = 0; f < 12; ++f) red[((wid - 1) * 12 + f) * 64 + lane] = acc[f];
    }
    __syncthreads();
    if (wid == 0) {
        const int b  = row0 >> 11;
        const int s0 = row0 & 2047;
        #pragma unroll
        for (int f = 0; f < 12; ++f) {
            f32x4 a = acc[f] + red[(0 * 12 + f) * 64 + lane]
                    + red[(1 * 12 + f) * 64 + lane] + red[(2 * 12 + f) * 64 + lane];
            const int md = f >> 2, nt = f & 3;
            if (md < 2) {
                // partQK[khalf][grow][128]: 16 lanes x 4B contiguous per (f,r)
                #pragma unroll
                for (int r = 0; r < 4; ++r)
                    partQK[((size_t)khalf * 8192 + row0 + g * 4 + r) * 128
                           + md * 64 + nt * 16 + l15] = a[r];
            } else {
                // partV[khalf][b*64+n][s]: transposed for coalesced k1b_v
                #pragma unroll
                for (int r = 0; r < 4; ++r)
                    partV[((size_t)khalf * 256 + b * 64 + nt * 16 + l15) * SS
                          + s0 + g * 4 + r] = a[r];
            }
        }
    }
}

// k1b_qk: Q/K = part0+part1 + bias (Q scaled); coalesced. 512 blocks.
__global__ __launch_bounds__(256) void k1b_qk(
    const float* __restrict__ partQK, const float* __restrict__ bq,
    const float* __restrict__ bk, __bf16* __restrict__ Qo, __bf16* __restrict__ Ko)
{
    int idx = blockIdx.x * 256 + threadIdx.x; // 0..131071
    int row = idx >> 4;
    int c8  = idx & 15;                       // 8-col chunk
    const float* p0 = partQK + (size_t)row * 128 + c8 * 8;
    const float* p1 = p0 + (size_t)8192 * 128;
    f32x4 a0 = *(const f32x4*)(p0)     + *(const f32x4*)(p1);
    f32x4 a1 = *(const f32x4*)(p0 + 4) + *(const f32x4*)(p1 + 4);
    const int mode = c8 >> 3;
    const float* bias = mode ? bk : bq;
    const float bscale = mode ? 1.0f : 0.03125f;
    const int cb = (c8 & 7) * 8;
    bf16x8 o;
    #pragma unroll
    for (int i = 0; i < 4; ++i) {
        o[i]     = (__bf16)(a0[i] + bias[cb + i] * bscale);
        o[i + 4] = (__bf16)(a1[i] + bias[cb + 4 + i] * bscale);
    }
    __bf16* dst = (mode ? Ko : Qo) + (size_t)row * DHEAD + cb;
    *(bf16x8*)dst = o;
}

// k1b_v: Vt = part0+part1 + bv; fully coalesced. 256 blocks.
__global__ __launch_bounds__(256) void k1b_v(
    const float* __restrict__ partV, const float* __restrict__ bv,
    __bf16* __restrict__ Vt)
{
    int idx = blockIdx.x * 256 + threadIdx.x; // 0..65535
    int bn = idx >> 8;                        // b*64+n
    int s  = (idx & 255) * 8;
    const float* p0 = partV + (size_t)bn * SS + s;
    const float* p1 = p0 + (size_t)256 * SS;
    f32x4 a0 = *(const f32x4*)(p0)     + *(const f32x4*)(p1);
    f32x4 a1 = *(const f32x4*)(p0 + 4) + *(const f32x4*)(p1 + 4);
    float bvl = bv[bn & 63];
    bf16x8 o;
    #pragma unroll
    for (int i = 0; i < 4; ++i) {
        o[i] = (__bf16)(a0[i] + bvl);
        o[i + 4] = (__bf16)(a1[i] + bvl);
    }
    *(bf16x8*)(Vt + (size_t)bn * SS + s) = o;
}

// ---------------- Kernel 2: column exp-sum partials (32 q-slices) -----------
// grid 2048 = 4b x 16 kg(128k) x 32 qs(64q); block 256 = 4 waves x 32k.
__global__ __launch_bounds__(256) void k2_cs(
    const __bf16* __restrict__ Qb, const __bf16* __restrict__ Kb,
    float* __restrict__ partial)
{
    const int tid = threadIdx.x;
    const int wid = tid >> 6;
    const int lane = tid & 63;
    const int l15 = lane & 15;
    const int g = lane >> 4;
    const int bx = blockIdx.x;
    const int b  = bx >> 9;
    const int rem = bx & 511;
    const int kg = rem >> 5;
    const int qs = rem & 31;
    const int k0 = kg * 128 + wid * 32;

    const __bf16* kp0 = Kb + ((size_t)(b * SS + k0 + l15)) * DHEAD + g * 8;
    bf16x8 ka00 = *(const bf16x8*)(kp0);
    bf16x8 ka01 = *(const bf16x8*)(kp0 + 32);
    const __bf16* kp1 = kp0 + 16 * DHEAD;
    bf16x8 ka10 = *(const bf16x8*)(kp1);
    bf16x8 ka11 = *(const bf16x8*)(kp1 + 32);

    f32x4 cs0 = (f32x4){0.f, 0.f, 0.f, 0.f};
    f32x4 cs1 = (f32x4){0.f, 0.f, 0.f, 0.f};

    #pragma unroll
    for (int j = 0; j < 4; ++j) {
        const int qrow = qs * 64 + j * 16 + l15;
        const __bf16* qp = Qb + ((size_t)(b * SS + qrow)) * DHEAD + g * 8;
        bf16x8 qb0 = *(const bf16x8*)(qp);
        bf16x8 qb1 = *(const bf16x8*)(qp + 32);
        f32x4 s0 = (f32x4){0.f, 0.f, 0.f, 0.f};
        s0 = MFMA16(ka00, qb0, s0);
        s0 = MFMA16(ka01, qb1, s0);
        f32x4 s1 = (f32x4){0.f, 0.f, 0.f, 0.f};
        s1 = MFMA16(ka10, qb0, s1);
        s1 = MFMA16(ka11, qb1, s1);
        #pragma unroll
        for (int r = 0; r < 4; ++r) {
            cs0[r] += __expf(s0[r]);
            cs1[r] += __expf(s1[r]);
        }
    }
    #pragma unroll
    for (int off = 1; off < 16; off <<= 1) {
        #pragma unroll
        for (int r = 0; r < 4; ++r) {
            cs0[r] += __shfl_xor(cs0[r], off);
            cs1[r] += __shfl_xor(cs1[r], off);
        }
    }
    if (l15 == 0) {
        float* pp = partial + (size_t)qs * (NB * SS) + b * SS + k0 + 4 * g;
        *(f32x4*)(pp)      = cs0;
        *(f32x4*)(pp + 16) = cs1;
    }
}

// k2b: r[k] = 1 / sum_qs partial[qs][k]
__global__ __launch_bounds__(256) void k2b(
    const float* __restrict__ partial, float* __restrict__ rarr)
{
    int i = blockIdx.x * 256 + threadIdx.x;   // 0..8191
    float s = 0.f;
    #pragma unroll
    for (int qs = 0; qs < 32; ++qs) s += partial[(size_t)qs * (NB * SS) + i];
    rarr[i] = 1.0f / s;
}

// ---------------- Kernel B: out += (exp(S).*r) @ V  (k-split 4) -------------
// grid 2048 = 4b x 128 q-tiles x 4 ks; block 256 = 4 waves x 128-k.
// Swapped QK mfma -> exp*r in registers -> in-register shuffle transpose
// (proven R6) -> PV MFMA. AtomicAdd epilogue (out pre-zeroed).
__global__ __launch_bounds__(256) void kb_pv(
    const __bf16* __restrict__ Qb, const __bf16* __restrict__ Kb,
    const __bf16* __restrict__ Vt, const float* __restrict__ rarr,
    float* __restrict__ out)
{
    __shared__ f32x4 red[4][4][64];           // 16 KB
    const int tid = threadIdx.x;
    const int wid = tid >> 6;
    const int lane = tid & 63;
    const int l15 = lane & 15;
    const int g = lane >> 4;
    const int bx = blockIdx.x;
    const int b  = bx >> 9;
    const int rem = bx & 511;
    const int q0 = (rem >> 2) * 16;
    const int ks = rem & 3;

    const __bf16* qp = Qb + ((size_t)(b * SS + q0 + l15)) * DHEAD + g * 8;
    bf16x8 qb0 = *(const bf16x8*)(qp);
    bf16x8 qb1 = *(const bf16x8*)(qp + 32);

    f32x4 acc[4];
    #pragma unroll
    for (int nt = 0; nt < 4; ++nt) acc[nt] = (f32x4){0.f, 0.f, 0.f, 0.f};
    const __bf16* vbase = Vt + (size_t)b * DHEAD * SS;
    const float* rrow = rarr + b * SS;

    #pragma unroll
    for (int c = 0; c < 4; ++c) {
        const int k0 = ks * 512 + wid * 128 + c * 32;
        const __bf16* kp0 = Kb + ((size_t)(b * SS + k0 + l15)) * DHEAD + g * 8;
        bf16x8 ka00 = *(const bf16x8*)(kp0);
        bf16x8 ka01 = *(const bf16x8*)(kp0 + 32);
        const __bf16* kp1 = kp0 + 16 * DHEAD;
        bf16x8 ka10 = *(const bf16x8*)(kp1);
        bf16x8 ka11 = *(const bf16x8*)(kp1 + 32);

        f32x4 s0 = (f32x4){0.f, 0.f, 0.f, 0.f};
        s0 = MFMA16(ka00, qb0, s0);
        s0 = MFMA16(ka01, qb1, s0);
        f32x4 s1 = (f32x4){0.f, 0.f, 0.f, 0.f};
        s1 = MFMA16(ka10, qb0, s1);
        s1 = MFMA16(ka11, qb1, s1);

        f32x4 rv0 = *(const f32x4*)(rrow + k0 + 4 * g);
        f32x4 rv1 = *(const f32x4*)(rrow + k0 + 16 + 4 * g);
        f32x4 e0, e1;
        #pragma unroll
        for (int r = 0; r < 4; ++r) {
            e0[r] = __expf(s0[r]) * rv0[r];
            e1[r] = __expf(s1[r]) * rv1[r];
        }
        // shuffle transpose: af[i] = P~[q=l15][k0 + 8g + i]
        bf16x8 af;
        #pragma unroll
        for (int i = 0; i < 8; ++i) {
            int src = l15 + 16 * ((2 * g + (i >> 2)) & 3);
            float v0 = __shfl(e0[i & 3], src);
            float v1 = __shfl(e1[i & 3], src);
            af[i] = (__bf16)(g < 2 ? v0 : v1);
        }
        #pragma unroll
        for (int nt = 0; nt < 4; ++nt) {
            bf16x8 vb = *(const bf16x8*)(vbase + (size_t)(nt * 16 + l15) * SS + k0 + g * 8);
            acc[nt] = MFMA16(af, vb, acc[nt]);
        }
    }
    #pragma unroll
    for (int nt = 0; nt < 4; ++nt) red[wid][nt][lane] = acc[nt];
    __syncthreads();
    if (wid == 0) {
        #pragma unroll
        for (int nt = 0; nt < 4; ++nt) {
            f32x4 a = red[0][nt][lane] + red[1][nt][lane]
                    + red[2][nt][lane] + red[3][nt][lane];
            #pragma unroll
            for (int r = 0; r < 4; ++r)
                atomicAdd(&out[((size_t)(b * SS + q0 + g * 4 + r)) * DHEAD + nt * 16 + l15], a[r]);
        }
    }
}

// ---------------- Kernel A: out += mask @ V  (k-split 4, LDS-staged) --------
// grid 2048 = 4b x 128 q-tiles x 4 ks; block 256 = 4 waves x 128-k.
// mask tile [16][512] f32 loaded fully coalesced (1KB/instr), converted bf16
// into LDS; A-frags via ds_read_b128. 8 blocks/CU = 32 waves/CU.
__global__ __launch_bounds__(256, 8) void ka_mv(
    const __bf16* __restrict__ Vt, const float* __restrict__ mask,
    float* __restrict__ out)
{
    __shared__ char smem[16 * 520 * 2];       // 16.6 KB; red alias (16 KB)
    __bf16* stage = (__bf16*)smem;
    const int tid = threadIdx.x;
    const int wid = tid >> 6;
    const int lane = tid & 63;
    const int l15 = lane & 15;
    const int g = lane >> 4;
    const int bx = blockIdx.x;
    const int b  = bx >> 9;
    const int rem = bx & 511;
    const int q0 = (rem >> 2) * 16;
    const int ks = rem & 3;

    // stage mask[q0..+16][ks*512..+512] f32 -> bf16, fully coalesced
    {
        const float* msrc = mask + ((size_t)(b * SS + q0)) * SS + ks * 512;
        #pragma unroll
        for (int it = 0; it < 8; ++it) {
            int idx = it * 256 + tid;
            int row = idx >> 7;
            int col = (idx & 127) * 4;
            f32x4 v = *(const f32x4*)(msrc + (size_t)row * SS + col);
            bf16x4 b4;
            #pragma unroll
            for (int i = 0; i < 4; ++i) b4[i] = (__bf16)v[i];
            *(bf16x4*)(stage + row * 520 + col) = b4;
        }
    }
    __syncthreads();

    f32x4 acc[4];
    #pragma unroll
    for (int nt = 0; nt < 4; ++nt) acc[nt] = (f32x4){0.f, 0.f, 0.f, 0.f};
    const __bf16* vbase = Vt + (size_t)b * DHEAD * SS + ks * 512 + wid * 128 + g * 8;

    #pragma unroll
    for (int c = 0; c < 4; ++c) {
        bf16x8 af = *(const bf16x8*)(stage + l15 * 520 + wid * 128 + c * 32 + g * 8);
        #pragma unroll
        for (int nt = 0; nt < 4; ++nt) {
            bf16x8 vb = *(const bf16x8*)(vbase + (size_t)(nt * 16 + l15) * SS + c * 32);
            acc[nt] = MFMA16(af, vb, acc[nt]);
        }
    }
    __syncthreads();                          // ds_reads done; alias red
    f32x4* red = (f32x4*)smem;                // [4][4][64] = 16 KB
    #pragma unroll
    for (int nt = 0; nt < 4; ++nt) red[(wid * 4 + nt) * 64 + lane] = acc[nt];
    __syncthreads();
    if (wid == 0) {
        #pragma unroll
        for (int nt = 0; nt < 4; ++nt) {
            f32x4 a = red[(0 * 4 + nt) * 64 + lane] + red[(1 * 4 + nt) * 64 + lane]
                    + red[(2 * 4 + nt) * 64 + lane] + red[(3 * 4 + nt) * 64 + lane];
            #pragma unroll
            for (int r = 0; r < 4; ++r)
                atomicAdd(&out[((size_t)(b * SS + q0 + g * 4 + r)) * DHEAD + nt * 16 + l15], a[r]);
        }
    }
}

extern "C" void kernel_launch(void* const* d_in, const int* in_sizes, int n_in,
                              void* d_out, int out_size, void* d_ws, size_t ws_size,
                              hipStream_t stream)
{
    const float* x    = (const float*)d_in[0];
    const float* mask = (const float*)d_in[1];
    const float* Wq   = (const float*)d_in[2];
    const float* bq   = (const float*)d_in[3];
    const float* Wk   = (const float*)d_in[4];
    const float* bk   = (const float*)d_in[5];
    const float* Wv   = (const float*)d_in[6];
    const float* bv   = (const float*)d_in[7];
    float* out = (float*)d_out;

    // ws layout (~17 MB): Qbf 1MB | Kbf 1MB | Vt 1MB | rarr 32KB(+pad) |
    //   csPart 1MB | Wt 384KB(+pad) | partQK 8MB @5M | partV 4MB @13M
    char* ws = (char*)d_ws;
    __bf16* Qbf   = (__bf16*)(ws);
    __bf16* Kbf   = (__bf16*)(ws + (1u << 20));
    __bf16* Vt    = (__bf16*)(ws + (2u << 20));
    float*  rarr  = (float*)(ws + (3u << 20));
    float*  csPart= (float*)(ws + (3u << 20) + (64u << 10));
    __bf16* Wt    = (__bf16*)(ws + (3u << 20) + (64u << 10) + (1u << 20));
    float*  partQK= (float*)(ws + (5u << 20));
    float*  partV = (float*)(ws + (13u << 20));

    hipMemsetAsync(out, 0, (size_t)out_size * sizeof(float), stream);
    k0_wt<<<96, 256, 0, stream>>>(Wq, Wk, Wv, Wt);
    k1_fused<<<dim3(512, 2), 256, 0, stream>>>(x, Wt, partQK, partV);
    k1b_qk<<<512, 256, 0, stream>>>(partQK, bq, bk, Qbf, Kbf);
    k1b_v<<<256, 256, 0, stream>>>(partV, bv, Vt);
    k2_cs<<<2048, 256, 0, stream>>>(Qbf, Kbf, csPart);
    k2b<<<32, 256, 0, stream>>>(csPart, rarr);
    kb_pv<<<2048, 256, 0, stream>>>(Qbf, Kbf, Vt, rarr, out);
    ka_mv<<<2048, 256, 0, stream>>>(Vt, mask, out);
}

// Round 8
// 94.460 us; speedup vs baseline: 1.2947x; 1.2947x over previous
//
#include <hip/hip_runtime.h>

#define NB 4
#define SS 2048
#define DMODEL 1024
#define DHEAD 64
// SCALE = sqrt(1024) = 32 exactly; folded into Wt for mode 0 (and bias at use).
// Softmax WITHOUT max subtraction: s ~ N(0,0.25), exp safe in f32.
// Softmax over the QUERY axis (reference quirk): r[k] = 1/sum_q exp(s[q,k]).
// out = (exp(S).*r + mask) @ V, computed in ONE merged GEMM kernel (kab).
// R8 theme: dispatch count is the dominant real cost (profiled dispatches carry
// ~38us fixed overhead; wall time tracks kernel count). 10 dispatches -> 4,
// no memset, no atomics.

typedef __bf16 bf16x8 __attribute__((ext_vector_type(8)));
typedef __bf16 bf16x4 __attribute__((ext_vector_type(4)));
typedef float f32x4 __attribute__((ext_vector_type(4)));

#define MFMA16(a, b, c) __builtin_amdgcn_mfma_f32_16x16x32_bf16((a), (b), (c), 0, 0, 0)

// ---------------- Kernel 0: transpose W -> Wt[mode][n][k] bf16 ----------------
__global__ __launch_bounds__(256) void k0_wt(
    const float* __restrict__ Wq, const float* __restrict__ Wk,
    const float* __restrict__ Wv, __bf16* __restrict__ Wt)
{
    int t = blockIdx.x * 256 + threadIdx.x;
    int m = t >> 13;
    int rem = t & 8191;
    int n  = rem >> 7;
    int k0 = (rem & 127) << 3;
    const float* W = (m == 0) ? Wq : (m == 1 ? Wk : Wv);
    const float s = (m == 0) ? 0.03125f : 1.0f;
    __bf16* o = Wt + ((size_t)m * 64 + n) * DMODEL + k0;
    #pragma unroll
    for (int i = 0; i < 8; ++i)
        o[i] = (__bf16)(W[(size_t)(k0 + i) * DHEAD + n] * s);
}

// ---------------- Kernel 1: fused Q/K/V projection (LDS-staged x) -----------
// grid 512, block 256 (4 waves, each a 256-k quarter). x tile [16][1024]
// staged f32->bf16 with fully-coalesced loads (16 f32x4/thread); A-frags via
// ds_read_b128 (stride 1032 bf16). Wt B-frags from L2. LDS reduce; epilogue
// stores Q/K/Vt.
#define XST 1032
__global__ __launch_bounds__(256) void k1_fused(
    const float* __restrict__ x, const __bf16* __restrict__ Wt,
    const float* __restrict__ bq, const float* __restrict__ bk,
    const float* __restrict__ bv,
    __bf16* __restrict__ Qo, __bf16* __restrict__ Ko, __bf16* __restrict__ Vt)
{
    __shared__ char smem[36864];              // stage 16x1032 bf16 (33KB) | red alias (36.9KB)
    __bf16* stage = (__bf16*)smem;
    const int tid = threadIdx.x;
    const int wid = tid >> 6;
    const int lane = tid & 63;
    const int l15 = lane & 15;
    const int g = lane >> 4;
    const int row0 = blockIdx.x * 16;

    // stage x[row0..+16][0..1024) f32 -> bf16, fully coalesced
    {
        const float* xsrc = x + (size_t)row0 * DMODEL;
        #pragma unroll
        for (int it = 0; it < 16; ++it) {
            int idx = it * 256 + tid;         // 0..4095
            int row = idx >> 8;               // 256 f32x4 chunks per row
            int col = (idx & 255) * 4;
            f32x4 v = *(const f32x4*)(xsrc + (size_t)row * DMODEL + col);
            bf16x4 b4;
            #pragma unroll
            for (int i = 0; i < 4; ++i) b4[i] = (__bf16)v[i];
            *(bf16x4*)(stage + row * XST + col) = b4;
        }
    }
    __syncthreads();

    f32x4 acc[12];
    #pragma unroll
    for (int f = 0; f < 12; ++f) acc[f] = (f32x4){0.f, 0.f, 0.f, 0.f};

    const __bf16* wbase = Wt + (size_t)l15 * DMODEL + wid * 256 + g * 8;
    #pragma unroll
    for (int c = 0; c < 8; ++c) {
        bf16x8 af = *(const bf16x8*)(stage + l15 * XST + wid * 256 + c * 32 + g * 8);
        #pragma unroll
        for (int f = 0; f < 12; ++f) {
            const int md = f >> 2, nt = f & 3;
            bf16x8 bfr = *(const bf16x8*)(wbase + (size_t)(md * 64 + nt * 16) * DMODEL + c * 32);
            acc[f] = MFMA16(af, bfr, acc[f]);
        }
    }
    __syncthreads();                          // ds_reads done; alias red over stage
    f32x4* red = (f32x4*)smem;                // [3][12][64] = 36.9 KB
    if (wid != 0) {
        #pragma unroll
        for (int f = 0; f < 12; ++f) red[((wid - 1) * 12 + f) * 64 + lane] = acc[f];
    }
    __syncthreads();
    if (wid == 0) {
        const int b  = row0 >> 11;
        const int s0 = row0 & 2047;
        #pragma unroll
        for (int f = 0; f < 12; ++f) {
            f32x4 a = acc[f] + red[(0 * 12 + f) * 64 + lane]
                    + red[(1 * 12 + f) * 64 + lane] + red[(2 * 12 + f) * 64 + lane];
            const int md = f >> 2, nt = f & 3;
            const int n = nt * 16 + l15;
            const float* bias = (md == 0) ? bq : (md == 1 ? bk : bv);
            const float bscale = (md == 0) ? 0.03125f : 1.0f;
            float bvl = bias[n] * bscale;
            #pragma unroll
            for (int r = 0; r < 4; ++r) {
                float o = a[r] + bvl;
                int sr = s0 + g * 4 + r;
                if (md == 0)      Qo[((size_t)b * SS + sr) * DHEAD + n] = (__bf16)o;
                else if (md == 1) Ko[((size_t)b * SS + sr) * DHEAD + n] = (__bf16)o;
                else              Vt[((size_t)b * DHEAD + n) * SS + sr] = (__bf16)o;
            }
        }
    }
}

// ---------------- Kernel 2: column exp-sum partials ----------------
// Swapped mfma(K,Q): lane holds S[q=l15][k=k0+4g+r] -> colsum in registers.
// grid 1024 = 4b x 16 kg(128k) x 16 qs(128q); block 256 = 4 waves x 32k.
// partial[qs][b][k] (16 x 8192 f32).
__global__ __launch_bounds__(256) void k2_cs(
    const __bf16* __restrict__ Qb, const __bf16* __restrict__ Kb,
    float* __restrict__ partial)
{
    const int tid = threadIdx.x;
    const int wid = tid >> 6;
    const int lane = tid & 63;
    const int l15 = lane & 15;
    const int g = lane >> 4;
    const int bx = blockIdx.x;
    const int b  = bx >> 8;
    const int rem = bx & 255;
    const int kg = rem >> 4;
    const int qs = rem & 15;
    const int k0 = kg * 128 + wid * 32;

    const __bf16* kp0 = Kb + ((size_t)(b * SS + k0 + l15)) * DHEAD + g * 8;
    bf16x8 ka00 = *(const bf16x8*)(kp0);
    bf16x8 ka01 = *(const bf16x8*)(kp0 + 32);
    const __bf16* kp1 = kp0 + 16 * DHEAD;
    bf16x8 ka10 = *(const bf16x8*)(kp1);
    bf16x8 ka11 = *(const bf16x8*)(kp1 + 32);

    f32x4 cs0 = (f32x4){0.f, 0.f, 0.f, 0.f};
    f32x4 cs1 = (f32x4){0.f, 0.f, 0.f, 0.f};

    #pragma unroll 2
    for (int j = 0; j < 8; ++j) {
        const int qrow = qs * 128 + j * 16 + l15;
        const __bf16* qp = Qb + ((size_t)(b * SS + qrow)) * DHEAD + g * 8;
        bf16x8 qb0 = *(const bf16x8*)(qp);
        bf16x8 qb1 = *(const bf16x8*)(qp + 32);
        f32x4 s0 = (f32x4){0.f, 0.f, 0.f, 0.f};
        s0 = MFMA16(ka00, qb0, s0);
        s0 = MFMA16(ka01, qb1, s0);
        f32x4 s1 = (f32x4){0.f, 0.f, 0.f, 0.f};
        s1 = MFMA16(ka10, qb0, s1);
        s1 = MFMA16(ka11, qb1, s1);
        #pragma unroll
        for (int r = 0; r < 4; ++r) {
            cs0[r] += __expf(s0[r]);
            cs1[r] += __expf(s1[r]);
        }
    }
    #pragma unroll
    for (int off = 1; off < 16; off <<= 1) {
        #pragma unroll
        for (int r = 0; r < 4; ++r) {
            cs0[r] += __shfl_xor(cs0[r], off);
            cs1[r] += __shfl_xor(cs1[r], off);
        }
    }
    if (l15 == 0) {
        float* pp = partial + (size_t)qs * (NB * SS) + b * SS + k0 + 4 * g;
        *(f32x4*)(pp)      = cs0;
        *(f32x4*)(pp + 16) = cs1;
    }
}

// ---------------- Kernel AB: out = (exp(S).*r + mask) @ V ----------------
// grid 512 = 4b x 128 q-tiles; block 512 = 8 waves, each a 256-k octant.
// Prologue (folds old k2b): r[k] = 1/sum(partials) into LDS; mask tile
// [16][2048] f32 -> bf16 staged fully coalesced. Main loop per 32-k chunk:
// swapped QK mfma -> exp*r (lane-local k) -> in-register shuffle transpose
// (R6-proven) -> + mask (ds_read) -> bf16 A-frag -> 4 PV MFMAs (single V
// pass for both terms). LDS reduce over 8 waves; direct stores.
#define MST 2072
__global__ __launch_bounds__(512) void kab(
    const __bf16* __restrict__ Qb, const __bf16* __restrict__ Kb,
    const __bf16* __restrict__ Vt, const float* __restrict__ mask,
    const float* __restrict__ part, float* __restrict__ out)
{
    __shared__ char smem[16 * MST * 2 + 8192];   // mask 64.8KB | r 8KB; red alias
    __bf16* mst = (__bf16*)smem;
    float* rl = (float*)(smem + 16 * MST * 2);
    const int tid = threadIdx.x;
    const int wid = tid >> 6;
    const int lane = tid & 63;
    const int l15 = lane & 15;
    const int g = lane >> 4;
    const int b  = blockIdx.x >> 7;
    const int q0 = (blockIdx.x & 127) * 16;

    // ---- r prologue: 4 k per thread, sum 16 partial slices ----
    {
        const int k = tid * 4;
        f32x4 s = (f32x4){0.f, 0.f, 0.f, 0.f};
        #pragma unroll
        for (int qs = 0; qs < 16; ++qs)
            s += *(const f32x4*)(part + (size_t)qs * (NB * SS) + b * SS + k);
        f32x4 rr;
        #pragma unroll
        for (int r = 0; r < 4; ++r) rr[r] = 1.0f / s[r];
        *(f32x4*)(rl + k) = rr;
    }
    // ---- stage mask[q0..+16][0..2048) f32 -> bf16, fully coalesced ----
    {
        const float* msrc = mask + ((size_t)(b * SS + q0)) * SS;
        #pragma unroll
        for (int it = 0; it < 16; ++it) {
            int idx = it * 512 + tid;         // 0..8191
            int row = idx >> 9;               // 512 f32x4 chunks per row
            int col = (idx & 511) * 4;
            f32x4 v = *(const f32x4*)(msrc + (size_t)row * SS + col);
            bf16x4 b4;
            #pragma unroll
            for (int i = 0; i < 4; ++i) b4[i] = (__bf16)v[i];
            *(bf16x4*)(mst + row * MST + col) = b4;
        }
    }
    __syncthreads();

    // hoisted Q B-frags (fixed q-tile)
    const __bf16* qp = Qb + ((size_t)(b * SS + q0 + l15)) * DHEAD + g * 8;
    bf16x8 qb0 = *(const bf16x8*)(qp);
    bf16x8 qb1 = *(const bf16x8*)(qp + 32);

    f32x4 acc[4];
    #pragma unroll
    for (int nt = 0; nt < 4; ++nt) acc[nt] = (f32x4){0.f, 0.f, 0.f, 0.f};
    const __bf16* vbase = Vt + (size_t)b * DHEAD * SS;
    const int ko = wid * 256;

    #pragma unroll 2
    for (int c = 0; c < 8; ++c) {
        const int k0g = ko + c * 32;
        const __bf16* kp0 = Kb + ((size_t)(b * SS + k0g + l15)) * DHEAD + g * 8;
        bf16x8 ka00 = *(const bf16x8*)(kp0);
        bf16x8 ka01 = *(const bf16x8*)(kp0 + 32);
        const __bf16* kp1 = kp0 + 16 * DHEAD;
        bf16x8 ka10 = *(const bf16x8*)(kp1);
        bf16x8 ka11 = *(const bf16x8*)(kp1 + 32);

        f32x4 s0 = (f32x4){0.f, 0.f, 0.f, 0.f};
        s0 = MFMA16(ka00, qb0, s0);
        s0 = MFMA16(ka01, qb1, s0);
        f32x4 s1 = (f32x4){0.f, 0.f, 0.f, 0.f};
        s1 = MFMA16(ka10, qb0, s1);
        s1 = MFMA16(ka11, qb1, s1);

        f32x4 rv0 = *(const f32x4*)(rl + k0g + 4 * g);
        f32x4 rv1 = *(const f32x4*)(rl + k0g + 16 + 4 * g);
        f32x4 e0, e1;
        #pragma unroll
        for (int r = 0; r < 4; ++r) {
            e0[r] = __expf(s0[r]) * rv0[r];
            e1[r] = __expf(s1[r]) * rv1[r];
        }
        // mask frag for [q=l15][k=k0g+8g..+8)
        bf16x8 mv = *(const bf16x8*)(mst + l15 * MST + k0g + g * 8);
        // shuffle transpose: af[i] = P~[q=l15][k0g + 8g + i] + mask
        bf16x8 af;
        #pragma unroll
        for (int i = 0; i < 8; ++i) {
            int src = l15 + 16 * ((2 * g + (i >> 2)) & 3);
            float v0 = __shfl(e0[i & 3], src);
            float v1 = __shfl(e1[i & 3], src);
            af[i] = (__bf16)((g < 2 ? v0 : v1) + (float)mv[i]);
        }
        #pragma unroll
        for (int nt = 0; nt < 4; ++nt) {
            bf16x8 vb = *(const bf16x8*)(vbase + (size_t)(nt * 16 + l15) * SS + k0g + g * 8);
            acc[nt] = MFMA16(af, vb, acc[nt]);
        }
    }
    __syncthreads();                          // all LDS reads done; alias red
    f32x4* red = (f32x4*)smem;                // [8][4][64] = 32 KB
    #pragma unroll
    for (int nt = 0; nt < 4; ++nt) red[(wid * 4 + nt) * 64 + lane] = acc[nt];
    __syncthreads();
    if (wid < 4) {
        const int nt = wid;
        f32x4 a = red[nt * 64 + lane];
        #pragma unroll
        for (int w = 1; w < 8; ++w) a += red[(w * 4 + nt) * 64 + lane];
        #pragma unroll
        for (int r = 0; r < 4; ++r)
            out[((size_t)(b * SS + q0 + g * 4 + r)) * DHEAD + nt * 16 + l15] = a[r];
    }
}

extern "C" void kernel_launch(void* const* d_in, const int* in_sizes, int n_in,
                              void* d_out, int out_size, void* d_ws, size_t ws_size,
                              hipStream_t stream)
{
    const float* x    = (const float*)d_in[0];
    const float* mask = (const float*)d_in[1];
    const float* Wq   = (const float*)d_in[2];
    const float* bq   = (const float*)d_in[3];
    const float* Wk   = (const float*)d_in[4];
    const float* bk   = (const float*)d_in[5];
    const float* Wv   = (const float*)d_in[6];
    const float* bv   = (const float*)d_in[7];
    float* out = (float*)d_out;

    // ws layout (<4MB): Qbf 1MB | Kbf 1MB | Vt 1MB | part 512KB | Wt 384KB
    char* ws = (char*)d_ws;
    __bf16* Qbf  = (__bf16*)(ws);
    __bf16* Kbf  = (__bf16*)(ws + (1u << 20));
    __bf16* Vt   = (__bf16*)(ws + (2u << 20));
    float*  part = (float*)(ws + (3u << 20));
    __bf16* Wt   = (__bf16*)(ws + (3u << 20) + (512u << 10));

    k0_wt<<<96, 256, 0, stream>>>(Wq, Wk, Wv, Wt);
    k1_fused<<<512, 256, 0, stream>>>(x, Wt, bq, bk, bv, Qbf, Kbf, Vt);
    k2_cs<<<1024, 256, 0, stream>>>(Qbf, Kbf, part);
    kab<<<512, 512, 0, stream>>>(Qbf, Kbf, Vt, mask, part, out);
}

// Round 9
// 65.718 us; speedup vs baseline: 1.8609x; 1.4373x over previous
//
#include <hip/hip_runtime.h>

#define NB 4
#define SS 2048
#define DMODEL 1024
#define DHEAD 64
// SCALE = sqrt(1024) = 32 exactly; folded into Wt3 for mode 0 (and bias at use).
// Softmax WITHOUT max subtraction: s ~ N(0,0.25), exp safe in f32.
// Softmax over the QUERY axis (reference quirk): r[k] = 1/sum_q exp(s[q,k]).
// R9 theme: the bottleneck is memory REQUEST RATE (16-line scatter per frag
// load), not bandwidth. Every global access is now <=1-2 lines per lane-group:
// fragment-contiguous W layout, LDS staging for Q/K/V/mask tiles.

typedef __bf16 bf16x8 __attribute__((ext_vector_type(8)));
typedef __bf16 bf16x4 __attribute__((ext_vector_type(4)));
typedef float f32x4 __attribute__((ext_vector_type(4)));

#define MFMA16(a, b, c) __builtin_amdgcn_mfma_f32_16x16x32_bf16((a), (b), (c), 0, 0, 0)

// ---------------- Kernel 0: W -> Wt3 fragment-contiguous bf16 ----------------
// Frag block (kc,f): 64 lanes x 8 bf16 = 1KB, lane-ordered so k1's B-frag load
// is `Wt3 + ((kc*12+f)<<9) + lane*8` = fully coalesced. kc=32-k chunk, f=mode*4+nt.
__global__ __launch_bounds__(256) void k0_wt3(
    const float* __restrict__ Wq, const float* __restrict__ Wk,
    const float* __restrict__ Wv, __bf16* __restrict__ Wt3)
{
    int idx = blockIdx.x * 256 + threadIdx.x;  // 0..24575
    int kc = idx / 768;
    int rem = idx - kc * 768;
    int f = rem >> 6;
    int lane = rem & 63;
    int g = lane >> 4, l15 = lane & 15;
    int mode = f >> 2, nt = f & 3;
    const float* W = (mode == 0) ? Wq : (mode == 1 ? Wk : Wv);
    const float s = (mode == 0) ? 0.03125f : 1.0f;
    int n = nt * 16 + l15;
    int k = kc * 32 + g * 8;
    bf16x8 o;
    #pragma unroll
    for (int i = 0; i < 8; ++i)
        o[i] = (__bf16)(W[(size_t)(k + i) * DHEAD + n] * s);
    *(bf16x8*)(Wt3 + (size_t)idx * 8) = o;
}

// ---------------- Kernel 1: fused Q/K/V projection ----------------
// grid 512, block 256 (4 waves, each a 256-k quarter). x tile LDS-staged
// (coalesced); W B-frags = coalesced 1KB loads from Wt3. LDS reduce; epilogue.
#define XST 1032
__global__ __launch_bounds__(256) void k1_fused(
    const float* __restrict__ x, const __bf16* __restrict__ Wt3,
    const float* __restrict__ bq, const float* __restrict__ bk,
    const float* __restrict__ bv,
    __bf16* __restrict__ Qo, __bf16* __restrict__ Ko, __bf16* __restrict__ Vt)
{
    __shared__ char smem[36864];              // stage 16x1032 bf16 (33KB) | red alias
    __bf16* stage = (__bf16*)smem;
    const int tid = threadIdx.x;
    const int wid = tid >> 6;
    const int lane = tid & 63;
    const int l15 = lane & 15;
    const int g = lane >> 4;
    const int row0 = blockIdx.x * 16;

    {   // stage x[row0..+16][0..1024) f32 -> bf16, fully coalesced
        const float* xsrc = x + (size_t)row0 * DMODEL;
        #pragma unroll
        for (int it = 0; it < 16; ++it) {
            int idx = it * 256 + tid;
            int row = idx >> 8;
            int col = (idx & 255) * 4;
            f32x4 v = *(const f32x4*)(xsrc + (size_t)row * DMODEL + col);
            bf16x4 b4;
            #pragma unroll
            for (int i = 0; i < 4; ++i) b4[i] = (__bf16)v[i];
            *(bf16x4*)(stage + row * XST + col) = b4;
        }
    }
    __syncthreads();

    f32x4 acc[12];
    #pragma unroll
    for (int f = 0; f < 12; ++f) acc[f] = (f32x4){0.f, 0.f, 0.f, 0.f};

    #pragma unroll
    for (int c = 0; c < 8; ++c) {
        bf16x8 af = *(const bf16x8*)(stage + l15 * XST + wid * 256 + c * 32 + g * 8);
        const int kc = wid * 8 + c;
        #pragma unroll
        for (int f = 0; f < 12; ++f) {
            bf16x8 bfr = *(const bf16x8*)(Wt3 + (((size_t)kc * 12 + f) << 9) + lane * 8);
            acc[f] = MFMA16(af, bfr, acc[f]);
        }
    }
    __syncthreads();
    f32x4* red = (f32x4*)smem;                // [3][12][64]
    if (wid != 0) {
        #pragma unroll
        for (int f = 0; f < 12; ++f) red[((wid - 1) * 12 + f) * 64 + lane] = acc[f];
    }
    __syncthreads();
    if (wid == 0) {
        const int b  = row0 >> 11;
        const int s0 = row0 & 2047;
        #pragma unroll
        for (int f = 0; f < 12; ++f) {
            f32x4 a = acc[f] + red[(0 * 12 + f) * 64 + lane]
                    + red[(1 * 12 + f) * 64 + lane] + red[(2 * 12 + f) * 64 + lane];
            const int md = f >> 2, nt = f & 3;
            const int n = nt * 16 + l15;
            const float* bias = (md == 0) ? bq : (md == 1 ? bk : bv);
            const float bscale = (md == 0) ? 0.03125f : 1.0f;
            float bvl = bias[n] * bscale;
            #pragma unroll
            for (int r = 0; r < 4; ++r) {
                float o = a[r] + bvl;
                int sr = s0 + g * 4 + r;
                if (md == 0)      Qo[((size_t)b * SS + sr) * DHEAD + n] = (__bf16)o;
                else if (md == 1) Ko[((size_t)b * SS + sr) * DHEAD + n] = (__bf16)o;
                else              Vt[((size_t)b * DHEAD + n) * SS + sr] = (__bf16)o;
            }
        }
    }
}

// ---------------- Kernel 2: column exp-sum partials ----------------
// grid 1024 = 4b x 16 kg(128k) x 16 qs(128q); block 256 = 4 waves x 32k.
// Q slice (128 rows, 16KB contiguous) staged to LDS; Q B-frags via ds_read.
// K A-frags hoisted (4 scatter loads/wave total - negligible).
#define QST 72
__global__ __launch_bounds__(256) void k2_cs(
    const __bf16* __restrict__ Qb, const __bf16* __restrict__ Kb,
    float* __restrict__ partial)
{
    __shared__ __bf16 qt[128 * QST];          // 18.4 KB
    const int tid = threadIdx.x;
    const int wid = tid >> 6;
    const int lane = tid & 63;
    const int l15 = lane & 15;
    const int g = lane >> 4;
    const int bx = blockIdx.x;
    const int b  = bx >> 8;
    const int rem = bx & 255;
    const int kg = rem >> 4;
    const int qs = rem & 15;
    const int k0 = kg * 128 + wid * 32;

    {   // stage Q rows [qs*128,+128): 16 KB contiguous
        const __bf16* qsrc = Qb + ((size_t)(b * SS + qs * 128)) * DHEAD;
        #pragma unroll
        for (int it = 0; it < 4; ++it) {
            int idx = it * 256 + tid;         // 16B chunk id, 0..1023
            int row = idx >> 3;
            int col = (idx & 7) * 8;
            *(bf16x8*)(qt + row * QST + col) = *(const bf16x8*)(qsrc + (size_t)idx * 8);
        }
    }

    const __bf16* kp0 = Kb + ((size_t)(b * SS + k0 + l15)) * DHEAD + g * 8;
    bf16x8 ka00 = *(const bf16x8*)(kp0);
    bf16x8 ka01 = *(const bf16x8*)(kp0 + 32);
    const __bf16* kp1 = kp0 + 16 * DHEAD;
    bf16x8 ka10 = *(const bf16x8*)(kp1);
    bf16x8 ka11 = *(const bf16x8*)(kp1 + 32);
    __syncthreads();

    f32x4 cs0 = (f32x4){0.f, 0.f, 0.f, 0.f};
    f32x4 cs1 = (f32x4){0.f, 0.f, 0.f, 0.f};

    #pragma unroll 2
    for (int j = 0; j < 8; ++j) {
        const __bf16* qr = qt + (j * 16 + l15) * QST + g * 8;
        bf16x8 qb0 = *(const bf16x8*)(qr);
        bf16x8 qb1 = *(const bf16x8*)(qr + 32);
        f32x4 s0 = (f32x4){0.f, 0.f, 0.f, 0.f};
        s0 = MFMA16(ka00, qb0, s0);
        s0 = MFMA16(ka01, qb1, s0);
        f32x4 s1 = (f32x4){0.f, 0.f, 0.f, 0.f};
        s1 = MFMA16(ka10, qb0, s1);
        s1 = MFMA16(ka11, qb1, s1);
        #pragma unroll
        for (int r = 0; r < 4; ++r) {
            cs0[r] += __expf(s0[r]);
            cs1[r] += __expf(s1[r]);
        }
    }
    #pragma unroll
    for (int off = 1; off < 16; off <<= 1) {
        #pragma unroll
        for (int r = 0; r < 4; ++r) {
            cs0[r] += __shfl_xor(cs0[r], off);
            cs1[r] += __shfl_xor(cs1[r], off);
        }
    }
    if (l15 == 0) {
        float* pp = partial + (size_t)qs * (NB * SS) + b * SS + k0 + 4 * g;
        *(f32x4*)(pp)      = cs0;
        *(f32x4*)(pp + 16) = cs1;
    }
}

// ---------------- Kernel AB: out = (exp(S).*r + mask) @ V ----------------
// grid 512 = 4b x 128 q-tiles; block 256 = 4 waves, each a 32-k slice of the
// current 128-k chunk (16 chunks). Per chunk, ALL staging is coalesced:
// K 16KB contiguous, V 64x256B rows, mask 16x512B rows (f32->bf16). Frags via
// ds_read (16B-aligned strides). Shuffle-transpose P (R6-proven) + mask ->
// single PV MFMA pass. r[k] prologue folds k2b. LDS reduce; direct stores.
#define KST 72
#define VST 136
#define MTS 136
__global__ __launch_bounds__(256) void kab(
    const __bf16* __restrict__ Qb, const __bf16* __restrict__ Kb,
    const __bf16* __restrict__ Vt, const float* __restrict__ mask,
    const float* __restrict__ part, float* __restrict__ out)
{
    __shared__ char smem[48384];
    __bf16* kt = (__bf16*)smem;                       // [128][72] 18432 B
    __bf16* vt = (__bf16*)(smem + 18432);             // [64][136] 17408 B
    __bf16* mt = (__bf16*)(smem + 18432 + 17408);     // [16][136]  4352 B
    float*  rl = (float*)(smem + 18432 + 17408 + 4352); // 2048 f32  8192 B
    const int tid = threadIdx.x;
    const int wid = tid >> 6;
    const int lane = tid & 63;
    const int l15 = lane & 15;
    const int g = lane >> 4;
    const int b  = blockIdx.x >> 7;
    const int q0 = (blockIdx.x & 127) * 16;

    {   // r prologue: 8 k per thread, sum 16 partial slices
        const int k = tid * 8;
        f32x4 sa = (f32x4){0.f, 0.f, 0.f, 0.f};
        f32x4 sb = (f32x4){0.f, 0.f, 0.f, 0.f};
        #pragma unroll
        for (int qs = 0; qs < 16; ++qs) {
            const float* pp = part + (size_t)qs * (NB * SS) + b * SS + k;
            sa += *(const f32x4*)(pp);
            sb += *(const f32x4*)(pp + 4);
        }
        f32x4 ra, rb;
        #pragma unroll
        for (int r = 0; r < 4; ++r) { ra[r] = 1.0f / sa[r]; rb[r] = 1.0f / sb[r]; }
        *(f32x4*)(rl + k) = ra;
        *(f32x4*)(rl + k + 4) = rb;
    }

    // hoisted Q B-frags (2 scatter loads per wave total)
    const __bf16* qp = Qb + ((size_t)(b * SS + q0 + l15)) * DHEAD + g * 8;
    bf16x8 qb0 = *(const bf16x8*)(qp);
    bf16x8 qb1 = *(const bf16x8*)(qp + 32);

    f32x4 acc[4];
    #pragma unroll
    for (int nt = 0; nt < 4; ++nt) acc[nt] = (f32x4){0.f, 0.f, 0.f, 0.f};

    for (int cc = 0; cc < 16; ++cc) {
        __syncthreads();                      // protect previous chunk reads
        {   // K: rows [cc*128,+128) x 64d = 16 KB CONTIGUOUS
            const __bf16* ksrc = Kb + ((size_t)b * SS + cc * 128) * DHEAD;
            #pragma unroll
            for (int it = 0; it < 4; ++it) {
                int idx = it * 256 + tid;
                int row = idx >> 3;
                int col = (idx & 7) * 8;
                *(bf16x8*)(kt + row * KST + col) = *(const bf16x8*)(ksrc + (size_t)idx * 8);
            }
            // V: 64 d-rows x 256 B segments
            const __bf16* vsrc = Vt + (size_t)b * DHEAD * SS + cc * 128;
            #pragma unroll
            for (int it = 0; it < 4; ++it) {
                int idx = it * 256 + tid;
                int row = idx >> 4;
                int col = (idx & 15) * 8;
                *(bf16x8*)(vt + row * VST + col) = *(const bf16x8*)(vsrc + (size_t)row * SS + col);
            }
            // mask: 16 q-rows x 512 B f32 segments -> bf16
            const float* msrc = mask + ((size_t)(b * SS + q0)) * SS + cc * 128;
            #pragma unroll
            for (int it = 0; it < 2; ++it) {
                int idx = it * 256 + tid;
                int row = idx >> 5;
                int col = (idx & 31) * 4;
                f32x4 v = *(const f32x4*)(msrc + (size_t)row * SS + col);
                bf16x4 b4;
                #pragma unroll
                for (int i = 0; i < 4; ++i) b4[i] = (__bf16)v[i];
                *(bf16x4*)(mt + row * MTS + col) = b4;
            }
        }
        __syncthreads();

        const int kl = wid * 32;              // wave's 32-k slice in chunk
        const __bf16* kr0 = kt + (kl + l15) * KST + g * 8;
        bf16x8 ka00 = *(const bf16x8*)(kr0);
        bf16x8 ka01 = *(const bf16x8*)(kr0 + 32);
        const __bf16* kr1 = kr0 + 16 * KST;
        bf16x8 ka10 = *(const bf16x8*)(kr1);
        bf16x8 ka11 = *(const bf16x8*)(kr1 + 32);

        f32x4 s0 = (f32x4){0.f, 0.f, 0.f, 0.f};
        s0 = MFMA16(ka00, qb0, s0);
        s0 = MFMA16(ka01, qb1, s0);
        f32x4 s1 = (f32x4){0.f, 0.f, 0.f, 0.f};
        s1 = MFMA16(ka10, qb0, s1);
        s1 = MFMA16(ka11, qb1, s1);

        const int kbase = cc * 128 + kl;
        f32x4 rv0 = *(const f32x4*)(rl + kbase + 4 * g);
        f32x4 rv1 = *(const f32x4*)(rl + kbase + 16 + 4 * g);
        f32x4 e0, e1;
        #pragma unroll
        for (int r = 0; r < 4; ++r) {
            e0[r] = __expf(s0[r]) * rv0[r];
            e1[r] = __expf(s1[r]) * rv1[r];
        }
        // mask frag [q=l15][k=kl+8g..+8)
        bf16x8 mv = *(const bf16x8*)(mt + l15 * MTS + kl + g * 8);
        // shuffle transpose: af[i] = P~[q=l15][kl + 8g + i] + mask
        bf16x8 af;
        #pragma unroll
        for (int i = 0; i < 8; ++i) {
            int src = l15 + 16 * ((2 * g + (i >> 2)) & 3);
            float v0 = __shfl(e0[i & 3], src);
            float v1 = __shfl(e1[i & 3], src);
            af[i] = (__bf16)((g < 2 ? v0 : v1) + (float)mv[i]);
        }
        #pragma unroll
        for (int nt = 0; nt < 4; ++nt) {
            bf16x8 vb = *(const bf16x8*)(vt + (nt * 16 + l15) * VST + kl + g * 8);
            acc[nt] = MFMA16(af, vb, acc[nt]);
        }
    }
    __syncthreads();
    f32x4* red = (f32x4*)smem;                // [4][4][64] = 16 KB alias over kt
    #pragma unroll
    for (int nt = 0; nt < 4; ++nt) red[(wid * 4 + nt) * 64 + lane] = acc[nt];
    __syncthreads();
    if (wid == 0) {
        #pragma unroll
        for (int nt = 0; nt < 4; ++nt) {
            f32x4 a = red[(0 * 4 + nt) * 64 + lane] + red[(1 * 4 + nt) * 64 + lane]
                    + red[(2 * 4 + nt) * 64 + lane] + red[(3 * 4 + nt) * 64 + lane];
            #pragma unroll
            for (int r = 0; r < 4; ++r)
                out[((size_t)(b * SS + q0 + g * 4 + r)) * DHEAD + nt * 16 + l15] = a[r];
        }
    }
}

extern "C" void kernel_launch(void* const* d_in, const int* in_sizes, int n_in,
                              void* d_out, int out_size, void* d_ws, size_t ws_size,
                              hipStream_t stream)
{
    const float* x    = (const float*)d_in[0];
    const float* mask = (const float*)d_in[1];
    const float* Wq   = (const float*)d_in[2];
    const float* bq   = (const float*)d_in[3];
    const float* Wk   = (const float*)d_in[4];
    const float* bk   = (const float*)d_in[5];
    const float* Wv   = (const float*)d_in[6];
    const float* bv   = (const float*)d_in[7];
    float* out = (float*)d_out;

    // ws layout (<4MB): Qbf 1MB | Kbf 1MB | Vt 1MB | part 512KB | Wt3 384KB
    char* ws = (char*)d_ws;
    __bf16* Qbf  = (__bf16*)(ws);
    __bf16* Kbf  = (__bf16*)(ws + (1u << 20));
    __bf16* Vt   = (__bf16*)(ws + (2u << 20));
    float*  part = (float*)(ws + (3u << 20));
    __bf16* Wt3  = (__bf16*)(ws + (3u << 20) + (512u << 10));

    k0_wt3<<<96, 256, 0, stream>>>(Wq, Wk, Wv, Wt3);
    k1_fused<<<512, 256, 0, stream>>>(x, Wt3, bq, bk, bv, Qbf, Kbf, Vt);
    k2_cs<<<1024, 256, 0, stream>>>(Qbf, Kbf, part);
    kab<<<512, 256, 0, stream>>>(Qbf, Kbf, Vt, mask, part, out);
}

// Round 10
// 57.374 us; speedup vs baseline: 2.1315x; 1.1454x over previous
//
#include <hip/hip_runtime.h>

#define NB 4
#define SS 2048
#define DMODEL 1024
#define DHEAD 64
// SCALE = sqrt(1024) = 32 exactly; folded into Wt3 for mode 0 (and bias at use).
// Softmax WITHOUT max subtraction: s ~ N(0,0.25), exp safe in f32.
// Softmax over the QUERY axis (reference quirk): r[k] = 1/sum_q exp(s[q,k]).
// R10 theme: K and V are stored FRAGMENT-CONTIGUOUS in global memory (like Wt3),
// so every MFMA fragment load in k2/kab is one coalesced 1KB instruction.
// kab's main loop is barrier-free (mask staged once; K/V straight from L2).

typedef __bf16 bf16x8 __attribute__((ext_vector_type(8)));
typedef __bf16 bf16x4 __attribute__((ext_vector_type(4)));
typedef float f32x4 __attribute__((ext_vector_type(4)));

#define MFMA16(a, b, c) __builtin_amdgcn_mfma_f32_16x16x32_bf16((a), (b), (c), 0, 0, 0)

// Kb3 frag addr: ((b*256 + t*2 + h) << 9) + lane*8 + i
//   t = k>>4 (16-k tile), h = d>>5 (d-half), lane = ((d&31)>>3)*16 + (k&15), i = d&7
// Vt3 frag addr: ((b*256 + kc*4 + nt) << 9) + lane*8 + i
//   kc = k>>5 (32-k chunk), nt = d>>4, lane = ((k&31)>>3)*16 + (d&15), i = k&7

// ---------------- Kernel 0: W -> Wt3 fragment-contiguous bf16 ----------------
__global__ __launch_bounds__(256) void k0_wt3(
    const float* __restrict__ Wq, const float* __restrict__ Wk,
    const float* __restrict__ Wv, __bf16* __restrict__ Wt3)
{
    int idx = blockIdx.x * 256 + threadIdx.x;  // 0..24575
    int kc = idx / 768;
    int rem = idx - kc * 768;
    int f = rem >> 6;
    int lane = rem & 63;
    int g = lane >> 4, l15 = lane & 15;
    int mode = f >> 2, nt = f & 3;
    const float* W = (mode == 0) ? Wq : (mode == 1 ? Wk : Wv);
    const float s = (mode == 0) ? 0.03125f : 1.0f;
    int n = nt * 16 + l15;
    int k = kc * 32 + g * 8;
    bf16x8 o;
    #pragma unroll
    for (int i = 0; i < 8; ++i)
        o[i] = (__bf16)(W[(size_t)(k + i) * DHEAD + n] * s);
    *(bf16x8*)(Wt3 + (size_t)idx * 8) = o;
}

// ---------------- Kernel 1: fused Q/K/V projection ----------------
// grid 512, block 256. x tile LDS-staged (coalesced); W B-frags coalesced from
// Wt3. Epilogue: Q row-major; K -> Kb3 frags; V -> Vt3 frags (scalar stores,
// wid==0 only, fire-and-forget).
#define XST 1032
__global__ __launch_bounds__(256) void k1_fused(
    const float* __restrict__ x, const __bf16* __restrict__ Wt3,
    const float* __restrict__ bq, const float* __restrict__ bk,
    const float* __restrict__ bv,
    __bf16* __restrict__ Qo, __bf16* __restrict__ Kb3, __bf16* __restrict__ Vt3)
{
    __shared__ char smem[36864];              // stage 16x1032 bf16 (33KB) | red alias
    __bf16* stage = (__bf16*)smem;
    const int tid = threadIdx.x;
    const int wid = tid >> 6;
    const int lane = tid & 63;
    const int l15 = lane & 15;
    const int g = lane >> 4;
    const int row0 = blockIdx.x * 16;

    {   // stage x[row0..+16][0..1024) f32 -> bf16, fully coalesced
        const float* xsrc = x + (size_t)row0 * DMODEL;
        #pragma unroll
        for (int it = 0; it < 16; ++it) {
            int idx = it * 256 + tid;
            int row = idx >> 8;
            int col = (idx & 255) * 4;
            f32x4 v = *(const f32x4*)(xsrc + (size_t)row * DMODEL + col);
            bf16x4 b4;
            #pragma unroll
            for (int i = 0; i < 4; ++i) b4[i] = (__bf16)v[i];
            *(bf16x4*)(stage + row * XST + col) = b4;
        }
    }
    __syncthreads();

    f32x4 acc[12];
    #pragma unroll
    for (int f = 0; f < 12; ++f) acc[f] = (f32x4){0.f, 0.f, 0.f, 0.f};

    #pragma unroll
    for (int c = 0; c < 8; ++c) {
        bf16x8 af = *(const bf16x8*)(stage + l15 * XST + wid * 256 + c * 32 + g * 8);
        const int kc = wid * 8 + c;
        #pragma unroll
        for (int f = 0; f < 12; ++f) {
            bf16x8 bfr = *(const bf16x8*)(Wt3 + (((size_t)kc * 12 + f) << 9) + lane * 8);
            acc[f] = MFMA16(af, bfr, acc[f]);
        }
    }
    __syncthreads();
    f32x4* red = (f32x4*)smem;                // [3][12][64]
    if (wid != 0) {
        #pragma unroll
        for (int f = 0; f < 12; ++f) red[((wid - 1) * 12 + f) * 64 + lane] = acc[f];
    }
    __syncthreads();
    if (wid == 0) {
        const int b  = row0 >> 11;
        const int s0 = row0 & 2047;
        const int soff = (s0 >> 3) & 2;       // for Vt3 lane group
        #pragma unroll
        for (int f = 0; f < 12; ++f) {
            f32x4 a = acc[f] + red[(0 * 12 + f) * 64 + lane]
                    + red[(1 * 12 + f) * 64 + lane] + red[(2 * 12 + f) * 64 + lane];
            const int md = f >> 2, nt = f & 3;
            const int n = nt * 16 + l15;
            const float* bias = (md == 0) ? bq : (md == 1 ? bk : bv);
            const float bscale = (md == 0) ? 0.03125f : 1.0f;
            float bvl = bias[n] * bscale;
            #pragma unroll
            for (int r = 0; r < 4; ++r) {
                float o = a[r] + bvl;
                int sr = s0 + g * 4 + r;
                if (md == 0) {
                    Qo[((size_t)b * SS + sr) * DHEAD + n] = (__bf16)o;
                } else if (md == 1) {
                    // Kb3: t = s0>>4, h = nt>>1, lane' = ((nt&1)*2 + (l15>>3))*16 + g*4+r, i = l15&7
                    size_t fid = (size_t)b * 256 + (s0 >> 4) * 2 + (nt >> 1);
                    int ln = ((nt & 1) * 2 + (l15 >> 3)) * 16 + g * 4 + r;
                    Kb3[(fid << 9) + ln * 8 + (l15 & 7)] = (__bf16)o;
                } else {
                    // Vt3: kc = s0>>5, lane' = (soff + ((g*4+r)>>3))*16 + l15, i = (g*4+r)&7
                    size_t fid = (size_t)b * 256 + (s0 >> 5) * 4 + nt;
                    int ln = (soff + ((g * 4 + r) >> 3)) * 16 + l15;
                    Vt3[(fid << 9) + ln * 8 + ((g * 4 + r) & 7)] = (__bf16)o;
                }
            }
        }
    }
}

// ---------------- Kernel 2: column exp-sum partials ----------------
// grid 1024 = 4b x 16 kg(128k) x 16 qs(128q); block 256 = 4 waves x 32k.
// Q slice staged contiguous -> LDS; K A-frags = coalesced 1KB loads from Kb3.
#define QST 72
__global__ __launch_bounds__(256) void k2_cs(
    const __bf16* __restrict__ Qb, const __bf16* __restrict__ Kb3,
    float* __restrict__ partial)
{
    __shared__ __bf16 qt[128 * QST];          // 18.4 KB
    const int tid = threadIdx.x;
    const int wid = tid >> 6;
    const int lane = tid & 63;
    const int l15 = lane & 15;
    const int g = lane >> 4;
    const int bx = blockIdx.x;
    const int b  = bx >> 8;
    const int rem = bx & 255;
    const int kg = rem >> 4;
    const int qs = rem & 15;
    const int k0 = kg * 128 + wid * 32;

    {   // stage Q rows [qs*128,+128): 16 KB contiguous
        const __bf16* qsrc = Qb + ((size_t)(b * SS + qs * 128)) * DHEAD;
        #pragma unroll
        for (int it = 0; it < 4; ++it) {
            int idx = it * 256 + tid;
            int row = idx >> 3;
            int col = (idx & 7) * 8;
            *(bf16x8*)(qt + row * QST + col) = *(const bf16x8*)(qsrc + (size_t)idx * 8);
        }
    }

    // K A-frags: 4 coalesced 1KB loads from Kb3
    const __bf16* kfr = Kb3 + (((size_t)b * 256 + (k0 >> 4) * 2) << 9) + lane * 8;
    bf16x8 ka00 = *(const bf16x8*)(kfr);
    bf16x8 ka01 = *(const bf16x8*)(kfr + 512);
    bf16x8 ka10 = *(const bf16x8*)(kfr + 1024);
    bf16x8 ka11 = *(const bf16x8*)(kfr + 1536);
    __syncthreads();

    f32x4 cs0 = (f32x4){0.f, 0.f, 0.f, 0.f};
    f32x4 cs1 = (f32x4){0.f, 0.f, 0.f, 0.f};

    #pragma unroll 2
    for (int j = 0; j < 8; ++j) {
        const __bf16* qr = qt + (j * 16 + l15) * QST + g * 8;
        bf16x8 qb0 = *(const bf16x8*)(qr);
        bf16x8 qb1 = *(const bf16x8*)(qr + 32);
        f32x4 s0 = (f32x4){0.f, 0.f, 0.f, 0.f};
        s0 = MFMA16(ka00, qb0, s0);
        s0 = MFMA16(ka01, qb1, s0);
        f32x4 s1 = (f32x4){0.f, 0.f, 0.f, 0.f};
        s1 = MFMA16(ka10, qb0, s1);
        s1 = MFMA16(ka11, qb1, s1);
        #pragma unroll
        for (int r = 0; r < 4; ++r) {
            cs0[r] += __expf(s0[r]);
            cs1[r] += __expf(s1[r]);
        }
    }
    #pragma unroll
    for (int off = 1; off < 16; off <<= 1) {
        #pragma unroll
        for (int r = 0; r < 4; ++r) {
            cs0[r] += __shfl_xor(cs0[r], off);
            cs1[r] += __shfl_xor(cs1[r], off);
        }
    }
    if (l15 == 0) {
        float* pp = partial + (size_t)qs * (NB * SS) + b * SS + k0 + 4 * g;
        *(f32x4*)(pp)      = cs0;
        *(f32x4*)(pp + 16) = cs1;
    }
}

// ---------------- Kernel AB: out = (exp(S).*r + mask) @ V ----------------
// grid 512 = 4b x 128 q-tiles; block 256 = 4 waves; wave wid owns contiguous
// k-range [wid*512,+512) = 16 independent 32-k steps. Prologue: r[k] into LDS
// + mask tile [16][2048] staged once (ONE barrier). Main loop BARRIER-FREE:
// 4 K-frag + 4 V-frag coalesced 1KB loads from L2, QK MFMA -> exp*r ->
// shuffle transpose (R6-proven) + mask (ds_read) -> 4 PV MFMAs.
#define MST 2056
__global__ __launch_bounds__(256) void kab(
    const __bf16* __restrict__ Qb, const __bf16* __restrict__ Kb3,
    const __bf16* __restrict__ Vt3, const float* __restrict__ mask,
    const float* __restrict__ part, float* __restrict__ out)
{
    __shared__ char smem[16 * MST * 2 + 8192];   // mask 65792B | rl 8192B; red alias
    __bf16* mt = (__bf16*)smem;
    float*  rl = (float*)(smem + 16 * MST * 2);
    const int tid = threadIdx.x;
    const int wid = tid >> 6;
    const int lane = tid & 63;
    const int l15 = lane & 15;
    const int g = lane >> 4;
    const int b  = blockIdx.x >> 7;
    const int q0 = (blockIdx.x & 127) * 16;

    {   // r prologue: 8 k per thread, sum 16 partial slices
        const int k = tid * 8;
        f32x4 sa = (f32x4){0.f, 0.f, 0.f, 0.f};
        f32x4 sb = (f32x4){0.f, 0.f, 0.f, 0.f};
        #pragma unroll
        for (int qs = 0; qs < 16; ++qs) {
            const float* pp = part + (size_t)qs * (NB * SS) + b * SS + k;
            sa += *(const f32x4*)(pp);
            sb += *(const f32x4*)(pp + 4);
        }
        f32x4 ra, rb;
        #pragma unroll
        for (int r = 0; r < 4; ++r) { ra[r] = 1.0f / sa[r]; rb[r] = 1.0f / sb[r]; }
        *(f32x4*)(rl + k) = ra;
        *(f32x4*)(rl + k + 4) = rb;
    }
    {   // stage mask[q0..+16][0..2048) f32 -> bf16, fully coalesced, once
        const float* msrc = mask + ((size_t)(b * SS + q0)) * SS;
        #pragma unroll
        for (int it = 0; it < 32; ++it) {
            int idx = it * 256 + tid;         // 0..8191 f32x4 chunks
            int row = idx >> 9;
            int col = (idx & 511) * 4;
            f32x4 v = *(const f32x4*)(msrc + (size_t)row * SS + col);
            bf16x4 b4;
            #pragma unroll
            for (int i = 0; i < 4; ++i) b4[i] = (__bf16)v[i];
            *(bf16x4*)(mt + row * MST + col) = b4;
        }
    }

    // hoisted Q B-frags (2 scatter loads per wave total)
    const __bf16* qp = Qb + ((size_t)(b * SS + q0 + l15)) * DHEAD + g * 8;
    bf16x8 qb0 = *(const bf16x8*)(qp);
    bf16x8 qb1 = *(const bf16x8*)(qp + 32);
    __syncthreads();                          // rl + mask ready

    f32x4 acc[4];
    #pragma unroll
    for (int nt = 0; nt < 4; ++nt) acc[nt] = (f32x4){0.f, 0.f, 0.f, 0.f};

    #pragma unroll 2
    for (int st = 0; st < 16; ++st) {
        const int kbase = wid * 512 + st * 32;
        // 4 coalesced K frag loads (16-k tiles T, T+1 x d-halves)
        const __bf16* kfr = Kb3 + (((size_t)b * 256 + (kbase >> 4) * 2) << 9) + lane * 8;
        bf16x8 ka00 = *(const bf16x8*)(kfr);
        bf16x8 ka01 = *(const bf16x8*)(kfr + 512);
        bf16x8 ka10 = *(const bf16x8*)(kfr + 1024);
        bf16x8 ka11 = *(const bf16x8*)(kfr + 1536);
        // 4 coalesced V frag loads (nt = 0..3)
        const __bf16* vfr = Vt3 + (((size_t)b * 256 + (kbase >> 5) * 4) << 9) + lane * 8;
        bf16x8 vb0 = *(const bf16x8*)(vfr);
        bf16x8 vb1 = *(const bf16x8*)(vfr + 512);
        bf16x8 vb2 = *(const bf16x8*)(vfr + 1024);
        bf16x8 vb3 = *(const bf16x8*)(vfr + 1536);

        f32x4 s0 = (f32x4){0.f, 0.f, 0.f, 0.f};
        s0 = MFMA16(ka00, qb0, s0);
        s0 = MFMA16(ka01, qb1, s0);
        f32x4 s1 = (f32x4){0.f, 0.f, 0.f, 0.f};
        s1 = MFMA16(ka10, qb0, s1);
        s1 = MFMA16(ka11, qb1, s1);

        f32x4 rv0 = *(const f32x4*)(rl + kbase + 4 * g);
        f32x4 rv1 = *(const f32x4*)(rl + kbase + 16 + 4 * g);
        f32x4 e0, e1;
        #pragma unroll
        for (int r = 0; r < 4; ++r) {
            e0[r] = __expf(s0[r]) * rv0[r];
            e1[r] = __expf(s1[r]) * rv1[r];
        }
        // mask frag [q=l15][k=kbase+8g..+8) from LDS
        bf16x8 mv = *(const bf16x8*)(mt + l15 * MST + kbase + g * 8);
        // shuffle transpose: af[i] = P~[q=l15][kbase + 8g + i] + mask
        bf16x8 af;
        #pragma unroll
        for (int i = 0; i < 8; ++i) {
            int src = l15 + 16 * ((2 * g + (i >> 2)) & 3);
            float v0 = __shfl(e0[i & 3], src);
            float v1 = __shfl(e1[i & 3], src);
            af[i] = (__bf16)((g < 2 ? v0 : v1) + (float)mv[i]);
        }
        acc[0] = MFMA16(af, vb0, acc[0]);
        acc[1] = MFMA16(af, vb1, acc[1]);
        acc[2] = MFMA16(af, vb2, acc[2]);
        acc[3] = MFMA16(af, vb3, acc[3]);
    }
    __syncthreads();
    f32x4* red = (f32x4*)smem;                // [4][4][64] = 16 KB alias
    #pragma unroll
    for (int nt = 0; nt < 4; ++nt) red[(wid * 4 + nt) * 64 + lane] = acc[nt];
    __syncthreads();
    if (wid == 0) {
        #pragma unroll
        for (int nt = 0; nt < 4; ++nt) {
            f32x4 a = red[(0 * 4 + nt) * 64 + lane] + red[(1 * 4 + nt) * 64 + lane]
                    + red[(2 * 4 + nt) * 64 + lane] + red[(3 * 4 + nt) * 64 + lane];
            #pragma unroll
            for (int r = 0; r < 4; ++r)
                out[((size_t)(b * SS + q0 + g * 4 + r)) * DHEAD + nt * 16 + l15] = a[r];
        }
    }
}

extern "C" void kernel_launch(void* const* d_in, const int* in_sizes, int n_in,
                              void* d_out, int out_size, void* d_ws, size_t ws_size,
                              hipStream_t stream)
{
    const float* x    = (const float*)d_in[0];
    const float* mask = (const float*)d_in[1];
    const float* Wq   = (const float*)d_in[2];
    const float* bq   = (const float*)d_in[3];
    const float* Wk   = (const float*)d_in[4];
    const float* bk   = (const float*)d_in[5];
    const float* Wv   = (const float*)d_in[6];
    const float* bv   = (const float*)d_in[7];
    float* out = (float*)d_out;

    // ws layout (<4MB): Qbf 1MB | Kb3 1MB | Vt3 1MB | part 512KB | Wt3 384KB
    char* ws = (char*)d_ws;
    __bf16* Qbf  = (__bf16*)(ws);
    __bf16* Kb3  = (__bf16*)(ws + (1u << 20));
    __bf16* Vt3  = (__bf16*)(ws + (2u << 20));
    float*  part = (float*)(ws + (3u << 20));
    __bf16* Wt3  = (__bf16*)(ws + (3u << 20) + (512u << 10));

    k0_wt3<<<96, 256, 0, stream>>>(Wq, Wk, Wv, Wt3);
    k1_fused<<<512, 256, 0, stream>>>(x, Wt3, bq, bk, bv, Qbf, Kb3, Vt3);
    k2_cs<<<1024, 256, 0, stream>>>(Qbf, Kb3, part);
    kab<<<512, 256, 0, stream>>>(Qbf, Kb3, Vt3, mask, part, out);
}

// Round 11
// 54.938 us; speedup vs baseline: 2.2260x; 1.0443x over previous
//
#include <hip/hip_runtime.h>

#define NB 4
#define SS 2048
#define DMODEL 1024
#define DHEAD 64
// SCALE = sqrt(1024) = 32 exactly; folded into Wt3 for mode 0 (and bias at use).
// Softmax WITHOUT max subtraction: s ~ N(0,0.25), exp safe in f32.
// Softmax over the QUERY axis (reference quirk): r[k] = 1/sum_q exp(s[q,k]).
// R11: (1) k1 epilogue stores routed LDS->coalesced (was 2B-scattered scalar
// stores = partial-line RMW); (2) kab: 8 waves, no mask LDS (mask enters via
// the shuffle network), barrier-free loop, 16 waves/CU.

typedef __bf16 bf16x8 __attribute__((ext_vector_type(8)));
typedef __bf16 bf16x4 __attribute__((ext_vector_type(4)));
typedef float f32x4 __attribute__((ext_vector_type(4)));

#define MFMA16(a, b, c) __builtin_amdgcn_mfma_f32_16x16x32_bf16((a), (b), (c), 0, 0, 0)

// Kb3 frag addr (elems): ((b*256 + t*2 + h) << 9) + ln*8 + i
//   t=k>>4, h=d>>5, ln=((d&31)>>3)*16 + (k&15), i=d&7
// Vt3 frag addr (elems): ((b*256 + kc*4 + nt) << 9) + ln*8 + i
//   kc=k>>5, nt=d>>4, ln=((k&31)>>3)*16 + (d&15), i=k&7

// ---------------- Kernel 0: W -> Wt3 fragment-contiguous bf16 ----------------
__global__ __launch_bounds__(256) void k0_wt3(
    const float* __restrict__ Wq, const float* __restrict__ Wk,
    const float* __restrict__ Wv, __bf16* __restrict__ Wt3)
{
    int idx = blockIdx.x * 256 + threadIdx.x;  // 0..24575
    int kc = idx / 768;
    int rem = idx - kc * 768;
    int f = rem >> 6;
    int lane = rem & 63;
    int g = lane >> 4, l15 = lane & 15;
    int mode = f >> 2, nt = f & 3;
    const float* W = (mode == 0) ? Wq : (mode == 1 ? Wk : Wv);
    const float s = (mode == 0) ? 0.03125f : 1.0f;
    int n = nt * 16 + l15;
    int k = kc * 32 + g * 8;
    bf16x8 o;
    #pragma unroll
    for (int i = 0; i < 8; ++i)
        o[i] = (__bf16)(W[(size_t)(k + i) * DHEAD + n] * s);
    *(bf16x8*)(Wt3 + (size_t)idx * 8) = o;
}

// ---------------- Kernel 1: fused Q/K/V projection ----------------
// grid 512, block 256. x tile LDS-staged (coalesced); W B-frags coalesced from
// Wt3. Epilogue: reduce -> LDS out-stage in TARGET layouts -> cooperative
// coalesced bf16x8 stores (Q 2KB, Kb3 2KB, Vt3 4x512B).
#define XST 1032
__global__ __launch_bounds__(256) void k1_fused(
    const float* __restrict__ x, const __bf16* __restrict__ Wt3,
    const float* __restrict__ bq, const float* __restrict__ bk,
    const float* __restrict__ bv,
    __bf16* __restrict__ Qo, __bf16* __restrict__ Kb3, __bf16* __restrict__ Vt3)
{
    __shared__ char smem[43008];              // stage 33KB | red alias 36.9KB | outstage 6KB
    __bf16* stage = (__bf16*)smem;
    __bf16* outQ = (__bf16*)(smem + 36864);   // [16][64]
    __bf16* outK = outQ + 1024;               // 2 frags x 512 elems
    __bf16* outV = outK + 1024;               // 4 x 256 elems
    const int tid = threadIdx.x;
    const int wid = tid >> 6;
    const int lane = tid & 63;
    const int l15 = lane & 15;
    const int g = lane >> 4;
    const int row0 = blockIdx.x * 16;
    const int b  = row0 >> 11;
    const int s0 = row0 & 2047;
    const int soff = (s0 >> 3) & 2;

    {   // stage x[row0..+16][0..1024) f32 -> bf16, fully coalesced
        const float* xsrc = x + (size_t)row0 * DMODEL;
        #pragma unroll
        for (int it = 0; it < 16; ++it) {
            int idx = it * 256 + tid;
            int row = idx >> 8;
            int col = (idx & 255) * 4;
            f32x4 v = *(const f32x4*)(xsrc + (size_t)row * DMODEL + col);
            bf16x4 b4;
            #pragma unroll
            for (int i = 0; i < 4; ++i) b4[i] = (__bf16)v[i];
            *(bf16x4*)(stage + row * XST + col) = b4;
        }
    }
    __syncthreads();

    f32x4 acc[12];
    #pragma unroll
    for (int f = 0; f < 12; ++f) acc[f] = (f32x4){0.f, 0.f, 0.f, 0.f};

    #pragma unroll
    for (int c = 0; c < 8; ++c) {
        bf16x8 af = *(const bf16x8*)(stage + l15 * XST + wid * 256 + c * 32 + g * 8);
        const int kc = wid * 8 + c;
        #pragma unroll
        for (int f = 0; f < 12; ++f) {
            bf16x8 bfr = *(const bf16x8*)(Wt3 + (((size_t)kc * 12 + f) << 9) + lane * 8);
            acc[f] = MFMA16(af, bfr, acc[f]);
        }
    }
    __syncthreads();
    f32x4* red = (f32x4*)smem;                // [3][12][64] alias over stage
    if (wid != 0) {
        #pragma unroll
        for (int f = 0; f < 12; ++f) red[((wid - 1) * 12 + f) * 64 + lane] = acc[f];
    }
    __syncthreads();
    if (wid == 0) {
        #pragma unroll
        for (int f = 0; f < 12; ++f) {
            f32x4 a = acc[f] + red[(0 * 12 + f) * 64 + lane]
                    + red[(1 * 12 + f) * 64 + lane] + red[(2 * 12 + f) * 64 + lane];
            const int md = f >> 2, nt = f & 3;
            const int n = nt * 16 + l15;
            const float* bias = (md == 0) ? bq : (md == 1 ? bk : bv);
            const float bscale = (md == 0) ? 0.03125f : 1.0f;
            float bvl = bias[n] * bscale;
            #pragma unroll
            for (int r = 0; r < 4; ++r) {
                float o = a[r] + bvl;
                int g4r = g * 4 + r;
                if (md == 0) {
                    outQ[g4r * 64 + n] = (__bf16)o;
                } else if (md == 1) {
                    int ln = ((nt & 1) * 2 + (l15 >> 3)) * 16 + g4r;
                    outK[(nt >> 1) * 512 + ln * 8 + (l15 & 7)] = (__bf16)o;
                } else {
                    outV[nt * 256 + ((g4r >> 3) * 16 + l15) * 8 + (g4r & 7)] = (__bf16)o;
                }
            }
        }
    }
    __syncthreads();
    // cooperative coalesced stores
    if (tid < 128) {
        *(bf16x8*)(Qo + ((size_t)b * SS + s0) * DHEAD + tid * 8) = *(bf16x8*)(outQ + tid * 8);
        int nt = tid >> 5, e = (tid & 31) * 8;
        *(bf16x8*)(Vt3 + (((size_t)(b * 256 + (s0 >> 5) * 4 + nt)) << 9) + soff * 128 + e)
            = *(bf16x8*)(outV + nt * 256 + e);
    } else {
        int t2 = tid - 128;
        *(bf16x8*)(Kb3 + (((size_t)b * 256 + (s0 >> 4) * 2) << 9) + t2 * 8) = *(bf16x8*)(outK + t2 * 8);
    }
}

// ---------------- Kernel 2: column exp-sum partials ----------------
// grid 1024 = 4b x 16 kg(128k) x 16 qs(128q); block 256 = 4 waves x 32k.
#define QST 72
__global__ __launch_bounds__(256) void k2_cs(
    const __bf16* __restrict__ Qb, const __bf16* __restrict__ Kb3,
    float* __restrict__ partial)
{
    __shared__ __bf16 qt[128 * QST];          // 18.4 KB
    const int tid = threadIdx.x;
    const int wid = tid >> 6;
    const int lane = tid & 63;
    const int l15 = lane & 15;
    const int g = lane >> 4;
    const int bx = blockIdx.x;
    const int b  = bx >> 8;
    const int rem = bx & 255;
    const int kg = rem >> 4;
    const int qs = rem & 15;
    const int k0 = kg * 128 + wid * 32;

    {   // stage Q rows [qs*128,+128): 16 KB contiguous
        const __bf16* qsrc = Qb + ((size_t)(b * SS + qs * 128)) * DHEAD;
        #pragma unroll
        for (int it = 0; it < 4; ++it) {
            int idx = it * 256 + tid;
            int row = idx >> 3;
            int col = (idx & 7) * 8;
            *(bf16x8*)(qt + row * QST + col) = *(const bf16x8*)(qsrc + (size_t)idx * 8);
        }
    }

    const __bf16* kfr = Kb3 + (((size_t)b * 256 + (k0 >> 4) * 2) << 9) + lane * 8;
    bf16x8 ka00 = *(const bf16x8*)(kfr);
    bf16x8 ka01 = *(const bf16x8*)(kfr + 512);
    bf16x8 ka10 = *(const bf16x8*)(kfr + 1024);
    bf16x8 ka11 = *(const bf16x8*)(kfr + 1536);
    __syncthreads();

    f32x4 cs0 = (f32x4){0.f, 0.f, 0.f, 0.f};
    f32x4 cs1 = (f32x4){0.f, 0.f, 0.f, 0.f};

    #pragma unroll 2
    for (int j = 0; j < 8; ++j) {
        const __bf16* qr = qt + (j * 16 + l15) * QST + g * 8;
        bf16x8 qb0 = *(const bf16x8*)(qr);
        bf16x8 qb1 = *(const bf16x8*)(qr + 32);
        f32x4 s0 = (f32x4){0.f, 0.f, 0.f, 0.f};
        s0 = MFMA16(ka00, qb0, s0);
        s0 = MFMA16(ka01, qb1, s0);
        f32x4 s1 = (f32x4){0.f, 0.f, 0.f, 0.f};
        s1 = MFMA16(ka10, qb0, s1);
        s1 = MFMA16(ka11, qb1, s1);
        #pragma unroll
        for (int r = 0; r < 4; ++r) {
            cs0[r] += __expf(s0[r]);
            cs1[r] += __expf(s1[r]);
        }
    }
    #pragma unroll
    for (int off = 1; off < 16; off <<= 1) {
        #pragma unroll
        for (int r = 0; r < 4; ++r) {
            cs0[r] += __shfl_xor(cs0[r], off);
            cs1[r] += __shfl_xor(cs1[r], off);
        }
    }
    if (l15 == 0) {
        float* pp = partial + (size_t)qs * (NB * SS) + b * SS + k0 + 4 * g;
        *(f32x4*)(pp)      = cs0;
        *(f32x4*)(pp + 16) = cs1;
    }
}

// ---------------- Kernel AB: out = (exp(S).*r + mask) @ V ----------------
// grid 512 = 4b x 128 q-tiles; block 512 = 8 waves; wave wid owns k-range
// [wid*256,+256) = 8 steps of 32. NO mask LDS: per step each lane loads a
// coalesced f32x8 of mask (row q0+(lane>>2), cols (lane&3)*8), and the frag
// value for (q=l15, k=8g+i) comes from lane l15*4+g via the same shuffle
// network as the e-values. Loop is barrier-free; LDS = rl 8KB + red 32KB.
__global__ __launch_bounds__(512) void kab(
    const __bf16* __restrict__ Qb, const __bf16* __restrict__ Kb3,
    const __bf16* __restrict__ Vt3, const float* __restrict__ mask,
    const float* __restrict__ part, float* __restrict__ out)
{
    __shared__ char smem[40960];              // rl 8KB | red 32KB
    float* rl = (float*)smem;
    f32x4* red = (f32x4*)(smem + 8192);       // [8][4][64]
    const int tid = threadIdx.x;
    const int wid = tid >> 6;
    const int lane = tid & 63;
    const int l15 = lane & 15;
    const int g = lane >> 4;
    const int b  = blockIdx.x >> 7;
    const int q0 = (blockIdx.x & 127) * 16;

    {   // r prologue: 4 k per thread (512 thr x 4 = 2048)
        const int k = tid * 4;
        f32x4 s = (f32x4){0.f, 0.f, 0.f, 0.f};
        #pragma unroll
        for (int qs = 0; qs < 16; ++qs)
            s += *(const f32x4*)(part + (size_t)qs * (NB * SS) + b * SS + k);
        f32x4 rr;
        #pragma unroll
        for (int r = 0; r < 4; ++r) rr[r] = 1.0f / s[r];
        *(f32x4*)(rl + k) = rr;
    }

    // hoisted Q B-frags
    const __bf16* qp = Qb + ((size_t)(b * SS + q0 + l15)) * DHEAD + g * 8;
    bf16x8 qb0 = *(const bf16x8*)(qp);
    bf16x8 qb1 = *(const bf16x8*)(qp + 32);
    __syncthreads();                          // rl ready

    f32x4 acc[4];
    #pragma unroll
    for (int nt = 0; nt < 4; ++nt) acc[nt] = (f32x4){0.f, 0.f, 0.f, 0.f};
    const float* mrow = mask + ((size_t)(b * SS + q0 + (lane >> 2))) * SS + (lane & 3) * 8;
    const int msrc = l15 * 4 + g;             // shuffle source lane for mask

    #pragma unroll 2
    for (int st = 0; st < 8; ++st) {
        const int kbase = wid * 256 + st * 32;
        const __bf16* kfr = Kb3 + (((size_t)b * 256 + (kbase >> 4) * 2) << 9) + lane * 8;
        bf16x8 ka00 = *(const bf16x8*)(kfr);
        bf16x8 ka01 = *(const bf16x8*)(kfr + 512);
        bf16x8 ka10 = *(const bf16x8*)(kfr + 1024);
        bf16x8 ka11 = *(const bf16x8*)(kfr + 1536);
        const __bf16* vfr = Vt3 + (((size_t)b * 256 + (kbase >> 5) * 4) << 9) + lane * 8;
        bf16x8 vb0 = *(const bf16x8*)(vfr);
        bf16x8 vb1 = *(const bf16x8*)(vfr + 512);
        bf16x8 vb2 = *(const bf16x8*)(vfr + 1024);
        bf16x8 vb3 = *(const bf16x8*)(vfr + 1536);
        f32x4 mk0 = *(const f32x4*)(mrow + kbase);
        f32x4 mk1 = *(const f32x4*)(mrow + kbase + 4);

        f32x4 s0 = (f32x4){0.f, 0.f, 0.f, 0.f};
        s0 = MFMA16(ka00, qb0, s0);
        s0 = MFMA16(ka01, qb1, s0);
        f32x4 s1 = (f32x4){0.f, 0.f, 0.f, 0.f};
        s1 = MFMA16(ka10, qb0, s1);
        s1 = MFMA16(ka11, qb1, s1);

        f32x4 rv0 = *(const f32x4*)(rl + kbase + 4 * g);
        f32x4 rv1 = *(const f32x4*)(rl + kbase + 16 + 4 * g);
        f32x4 e0, e1;
        #pragma unroll
        for (int r = 0; r < 4; ++r) {
            e0[r] = __expf(s0[r]) * rv0[r];
            e1[r] = __expf(s1[r]) * rv1[r];
        }
        // shuffle transpose: af[i] = P~[q=l15][kbase+8g+i] + mask[q=l15][kbase+8g+i]
        bf16x8 af;
        #pragma unroll
        for (int i = 0; i < 8; ++i) {
            int src = l15 + 16 * ((2 * g + (i >> 2)) & 3);
            float v0 = __shfl(e0[i & 3], src);
            float v1 = __shfl(e1[i & 3], src);
            float mval = __shfl((i < 4 ? mk0[i & 3] : mk1[i & 3]), msrc);
            af[i] = (__bf16)((g < 2 ? v0 : v1) + mval);
        }
        acc[0] = MFMA16(af, vb0, acc[0]);
        acc[1] = MFMA16(af, vb1, acc[1]);
        acc[2] = MFMA16(af, vb2, acc[2]);
        acc[3] = MFMA16(af, vb3, acc[3]);
    }
    __syncthreads();
    #pragma unroll
    for (int nt = 0; nt < 4; ++nt) red[(wid * 4 + nt) * 64 + lane] = acc[nt];
    __syncthreads();
    // reduce 8 waves; stage out tile [16][64] f32 in LDS; coalesced stores
    float* outO = (float*)smem;               // 4KB alias over rl (rl dead)
    if (wid < 4) {
        const int nt = wid;
        f32x4 a = red[nt * 64 + lane];
        #pragma unroll
        for (int w = 1; w < 8; ++w) a += red[(w * 4 + nt) * 64 + lane];
        #pragma unroll
        for (int r = 0; r < 4; ++r)
            outO[(g * 4 + r) * 64 + nt * 16 + l15] = a[r];
    }
    __syncthreads();
    if (tid < 256) {
        int row = tid >> 4, col = (tid & 15) * 4;
        *(f32x4*)(out + ((size_t)(b * SS + q0 + row)) * DHEAD + col)
            = *(const f32x4*)(outO + row * 64 + col);
    }
}

extern "C" void kernel_launch(void* const* d_in, const int* in_sizes, int n_in,
                              void* d_out, int out_size, void* d_ws, size_t ws_size,
                              hipStream_t stream)
{
    const float* x    = (const float*)d_in[0];
    const float* mask = (const float*)d_in[1];
    const float* Wq   = (const float*)d_in[2];
    const float* bq   = (const float*)d_in[3];
    const float* Wk   = (const float*)d_in[4];
    const float* bk   = (const float*)d_in[5];
    const float* Wv   = (const float*)d_in[6];
    const float* bv   = (const float*)d_in[7];
    float* out = (float*)d_out;

    // ws layout (<4MB): Qbf 1MB | Kb3 1MB | Vt3 1MB | part 512KB | Wt3 384KB
    char* ws = (char*)d_ws;
    __bf16* Qbf  = (__bf16*)(ws);
    __bf16* Kb3  = (__bf16*)(ws + (1u << 20));
    __bf16* Vt3  = (__bf16*)(ws + (2u << 20));
    float*  part = (float*)(ws + (3u << 20));
    __bf16* Wt3  = (__bf16*)(ws + (3u << 20) + (512u << 10));

    k0_wt3<<<96, 256, 0, stream>>>(Wq, Wk, Wv, Wt3);
    k1_fused<<<512, 256, 0, stream>>>(x, Wt3, bq, bk, bv, Qbf, Kb3, Vt3);
    k2_cs<<<1024, 256, 0, stream>>>(Qbf, Kb3, part);
    kab<<<512, 512, 0, stream>>>(Qbf, Kb3, Vt3, mask, part, out);
}